// Round 3
// baseline (639.337 us; speedup 1.0000x reference)
//
#include <hip/hip_runtime.h>
#include <hip/hip_bf16.h>
#include <stdint.h>

// y = x @ quant(w).T + bias
//   x: (8192, 4096) fp32   w: (4096, 4096) fp32 (OUT, IN)   bias: (4096,) fp32
// R3: minimal chain — absmax kernel + fused quant(w)/cvt(x) kernel; gemm
// identical to R2 (rotation-swizzled LDS, 0 bank conflicts, 716 TF).

using short8  = __attribute__((ext_vector_type(8))) short;   // 8 bf16 = 4 VGPR
using float4v = __attribute__((ext_vector_type(4))) float;   // 4 fp32

// ---------- helpers ----------

__device__ __forceinline__ unsigned short f2bf(float f) {
    union { float f; uint32_t u; } v; v.f = f;
    uint32_t u = v.u;
    u += 0x7fffu + ((u >> 16) & 1u);   // RNE
    return (unsigned short)(u >> 16);
}

__device__ __forceinline__ void gload_lds16(const unsigned short* g, unsigned short* l) {
    __builtin_amdgcn_global_load_lds(
        (const __attribute__((address_space(1))) void*)g,
        (__attribute__((address_space(3))) void*)l,
        16, 0, 0);
}

// ---------- pre-pass 1: absmax(w) ----------

__global__ void absmax_kernel(const float* __restrict__ w, int n4,
                              unsigned int* __restrict__ amax_out) {
    const float4* w4 = (const float4*)w;
    float m = 0.f;
    const int stride = gridDim.x * blockDim.x;
    #pragma unroll 2
    for (int i = blockIdx.x * blockDim.x + threadIdx.x; i < n4; i += stride) {
        float4 v = w4[i];
        m = fmaxf(m, fmaxf(fmaxf(fabsf(v.x), fabsf(v.y)), fmaxf(fabsf(v.z), fabsf(v.w))));
    }
    #pragma unroll
    for (int off = 32; off > 0; off >>= 1)
        m = fmaxf(m, __shfl_down(m, off, 64));
    __shared__ float smax[4];
    int lane = threadIdx.x & 63, wv = threadIdx.x >> 6;
    if (lane == 0) smax[wv] = m;
    __syncthreads();
    if (threadIdx.x == 0) {
        float bm = fmaxf(fmaxf(smax[0], smax[1]), fmaxf(smax[2], smax[3]));
        atomicMax(amax_out, __float_as_uint(bm));  // vals >= 0: uint order == float order
    }
}

// ---------- pre-pass 2: quant/dequant w -> bf16 (blocks [0,QB)) + x -> bf16 ([QB,QB+CBK)) ----------

#define QB  1024
#define CBK 2048

__global__ void quantcvt_kernel(const float* __restrict__ w, int wn4,
                                const unsigned int* __restrict__ amax_bits,
                                ushort4* __restrict__ wq,
                                const float4* __restrict__ x, ushort4* __restrict__ xb, int xn4) {
    if (blockIdx.x < QB) {
        if (wn4 == 0) return;
        const float amax  = __uint_as_float(*amax_bits);
        const float scale = amax / 127.0f;
        const float inv   = 1.0f / scale;
        const float4* w4 = (const float4*)w;
        const int stride = QB * blockDim.x;
        #pragma unroll 2
        for (int i = blockIdx.x * blockDim.x + threadIdx.x; i < wn4; i += stride) {
            float4 v = w4[i];
            float q0 = fminf(fmaxf(rintf(v.x * inv), -127.f), 127.f);
            float q1 = fminf(fmaxf(rintf(v.y * inv), -127.f), 127.f);
            float q2 = fminf(fmaxf(rintf(v.z * inv), -127.f), 127.f);
            float q3 = fminf(fmaxf(rintf(v.w * inv), -127.f), 127.f);
            ushort4 o;
            o.x = f2bf(q0 * scale); o.y = f2bf(q1 * scale);
            o.z = f2bf(q2 * scale); o.w = f2bf(q3 * scale);
            wq[i] = o;
        }
    } else {
        const int stride = CBK * blockDim.x;
        #pragma unroll 2
        for (int i = (blockIdx.x - QB) * blockDim.x + threadIdx.x; i < xn4; i += stride) {
            float4 v = x[i];
            ushort4 o;
            o.x = f2bf(v.x); o.y = f2bf(v.y); o.z = f2bf(v.z); o.w = f2bf(v.w);
            xb[i] = o;
        }
    }
}

// ---------- GEMM: C(MxN) = A(MxK) * B(NxK)^T + bias ----------
// 128x128 block tile, BK=32, 256 threads (2x2 waves), 4x4 16x16x32 MFMA/wave.
// LDS layout: per 16-row/1KB region, chunk position p = 4*r + ((kc + (r>>1)) & 3)
// (16B chunks). Rotation makes each quarter-wave ds_read_b128 phase hit all 8
// bank-groups exactly 2x (2-way aliasing is free on gfx950 — m136; verified R2:
// SQ_LDS_BANK_CONFLICT 3.35e7 -> 0).

__global__ __launch_bounds__(256) void gemm_bt(
    const unsigned short* __restrict__ A,   // M x K bf16
    const unsigned short* __restrict__ B,   // N x K bf16
    const float* __restrict__ bias,
    float* __restrict__ C,                  // M x N fp32
    int M, int N, int K)
{
    __shared__ __align__(16) unsigned short As[128 * 32];   // 8 KB
    __shared__ __align__(16) unsigned short Bs[128 * 32];   // 8 KB

    const int tid  = threadIdx.x;
    const int lane = tid & 63;
    const int wave = tid >> 6;
    const int wm   = wave >> 1;
    const int wn   = wave & 1;

    const int bm = blockIdx.y * 128;
    const int bn = blockIdx.x * 128;

    // staging: lane l of each 1KB region -> row l>>2 (of 16), global kc rotated
    const int srow = wave * 32 + (lane >> 2);
    const int skc  = (((lane & 3) - (lane >> 3)) & 3) * 8;

    const unsigned short* Ag0 = A + (size_t)(bm + srow) * K + skc;
    const unsigned short* Ag1 = Ag0 + (size_t)16 * K;
    const unsigned short* Bg0 = B + (size_t)(bn + srow) * K + skc;
    const unsigned short* Bg1 = Bg0 + (size_t)16 * K;

    unsigned short* sA0 = As + wave * 1024;
    unsigned short* sA1 = sA0 + 512;
    unsigned short* sB0 = Bs + wave * 1024;
    unsigned short* sB1 = sB0 + 512;

    // fragment read: row r = lane&15, chunk c = lane>>4; p = 4r + ((c + (r>>1)) & 3)
    const int frow = lane & 15;
    const int fc   = lane >> 4;
    const int poff = (frow * 4 + ((fc + (frow >> 1)) & 3)) * 8;
    const unsigned short* pa = As + wm * 64 * 32 + poff;
    const unsigned short* pb = Bs + wn * 64 * 32 + poff;

    float4v acc[4][4];
    const float4v zero = {0.f, 0.f, 0.f, 0.f};
    #pragma unroll
    for (int i = 0; i < 4; i++)
        #pragma unroll
        for (int j = 0; j < 4; j++) acc[i][j] = zero;

    for (int k0 = 0; k0 < K; k0 += 32) {
        gload_lds16(Ag0, sA0);
        gload_lds16(Ag1, sA1);
        gload_lds16(Bg0, sB0);
        gload_lds16(Bg1, sB1);
        Ag0 += 32; Ag1 += 32; Bg0 += 32; Bg1 += 32;
        __syncthreads();

        short8 a[4], b[4];
        #pragma unroll
        for (int i = 0; i < 4; i++) a[i] = *(const short8*)(pa + i * 512);
        #pragma unroll
        for (int j = 0; j < 4; j++) b[j] = *(const short8*)(pb + j * 512);

        #pragma unroll
        for (int i = 0; i < 4; i++)
            #pragma unroll
            for (int j = 0; j < 4; j++)
                acc[i][j] = __builtin_amdgcn_mfma_f32_16x16x32_bf16(a[i], b[j], acc[i][j], 0, 0, 0);

        __syncthreads();
    }

    // epilogue: C/D layout col=lane&15, row=(lane>>4)*4+reg
    const int quad = lane >> 4;
    const int cl   = lane & 15;
    #pragma unroll
    for (int j = 0; j < 4; j++) {
        const int gc = bn + wn * 64 + j * 16 + cl;
        const float bs = bias[gc];
        #pragma unroll
        for (int i = 0; i < 4; i++) {
            const int gr = bm + wm * 64 + i * 16 + quad * 4;
            float* cp = C + (size_t)gr * N + gc;
            #pragma unroll
            for (int r = 0; r < 4; r++)
                cp[(size_t)r * N] = acc[i][j][r] + bs;
        }
    }
}

// ---------- launch ----------

extern "C" void kernel_launch(void* const* d_in, const int* in_sizes, int n_in,
                              void* d_out, int out_size, void* d_ws, size_t ws_size,
                              hipStream_t stream) {
    const float* x    = (const float*)d_in[0];   // (M, K)
    const float* w    = (const float*)d_in[1];   // (N, K)
    const float* bias = (const float*)d_in[2];   // (N,)
    float* out = (float*)d_out;

    const int N = 4096, K = 4096;
    const int M = in_sizes[0] / K;               // 8192

    // workspace: [256B amax | wq bf16 N*K | xb bf16 chunk]
    const size_t wq_off   = 256;
    const size_t wq_bytes = (size_t)N * K * 2;
    unsigned int*   amax = (unsigned int*)d_ws;
    unsigned short* wq   = (unsigned short*)((char*)d_ws + wq_off);
    unsigned short* xb   = (unsigned short*)((char*)d_ws + wq_off + wq_bytes);

    size_t avail = (ws_size > wq_off + wq_bytes) ? ws_size - wq_off - wq_bytes : 0;
    int nch = 1;
    while (nch < 64 && (size_t)(M / nch) * K * 2 > avail) nch <<= 1;
    const int crows = M / nch;

    hipMemsetAsync(d_ws, 0, 256, stream);
    absmax_kernel<<<2048, 256, 0, stream>>>(w, (N * K) / 4, amax);

    if (nch == 1) {
        quantcvt_kernel<<<QB + CBK, 256, 0, stream>>>(
            w, (N * K) / 4, amax, (ushort4*)wq,
            (const float4*)x, (ushort4*)xb, (M * K) / 4);
        dim3 grid(N / 128, M / 128);
        gemm_bt<<<grid, 256, 0, stream>>>(xb, wq, bias, out, M, N, K);
    } else {
        quantcvt_kernel<<<QB + CBK, 256, 0, stream>>>(
            w, (N * K) / 4, amax, (ushort4*)wq,
            (const float4*)x, (ushort4*)xb, 0);
        for (int c = 0; c < nch; c++) {
            const float* xc = x + (size_t)c * crows * K;
            quantcvt_kernel<<<QB + CBK, 256, 0, stream>>>(
                nullptr, 0, amax, nullptr,
                (const float4*)xc, (ushort4*)xb, (crows * K) / 4);
            dim3 grid(N / 128, crows / 128);
            gemm_bt<<<grid, 256, 0, stream>>>(xb, wq, bias, out + (size_t)c * crows * N,
                                              crows, N, K);
        }
    }
}